// Round 3
// baseline (258.270 us; speedup 1.0000x reference)
//
#include <hip/hip_runtime.h>

// ConvCaps EM-routing, MI355X. 392 independent problems, one 512-thread block each.
// Thread = (o = t&31 out-cap, kc = t>>5 of 16 k-chunks, 18 k each).
// __launch_bounds__(512,4): reg budget 128/thread -- kernel is register-bound;
// 1024-thread variant spilled (675 MB FETCH). Occupancy is LDS-bound at
// 2 blocks/CU and the grid is only 392 blocks (~3 waves/SIMD), so stalls must
// be hidden by ILP, not TLP: the E-loop processes TWO k's as explicitly
// interleaved independent chains (dual-k), using the 64 spare VGPRs
// (compiler used 64 of the 128 budget).
// Fused E+M: votes recomputed only 3x (M0, E0+M1, E1+M2) using unnormalized
// moments  mean = S(uv)/(rs+eps), var = S(uv^2)/(rs+eps) - m^2(2-S1),
// u_k = softmax_o(ln_ap)*c_k, c_k = a/(a+eps). r-matrix never materialized.
// Softmax 32-lane reduces: DPP basis {xor1,xor2,xor7,xor15} + ds_swizzle xor16.

namespace {

constexpr int NKK = 288;
constexpr float EPSF = 1e-8f;
constexpr float LN2PI = 1.8378770664093453f;

__device__ __forceinline__ float fastrcp(float x) { return __builtin_amdgcn_rcpf(x); }

// DPP lane permute (VALU pipe). CTRL: 0xB1=quad_perm xor1, 0x4E=quad_perm xor2,
// 0x141=row_half_mirror (xor7), 0x140=row_mirror (xor15).
template <int CTRL>
__device__ __forceinline__ float dppf(float x) {
    return __int_as_float(__builtin_amdgcn_update_dpp(
        __float_as_int(x), __float_as_int(x), CTRL, 0xF, 0xF, false));
}
// ds_swizzle xor16 within each 32-lane group (bitmode: xor=16, and=0x1F).
__device__ __forceinline__ float swz16(float x) {
    return __int_as_float(__builtin_amdgcn_ds_swizzle(__float_as_int(x), 0x401F));
}

// Dual interleaved 32-lane reduces: two independent chains in flight.
__device__ __forceinline__ void redmax32x2(float& a, float& b) {
    float ta, tb;
    ta = dppf<0xB1>(a);  tb = dppf<0xB1>(b);  a = fmaxf(a, ta); b = fmaxf(b, tb);
    ta = dppf<0x4E>(a);  tb = dppf<0x4E>(b);  a = fmaxf(a, ta); b = fmaxf(b, tb);
    ta = dppf<0x141>(a); tb = dppf<0x141>(b); a = fmaxf(a, ta); b = fmaxf(b, tb);
    ta = dppf<0x140>(a); tb = dppf<0x140>(b); a = fmaxf(a, ta); b = fmaxf(b, tb);
    ta = swz16(a);       tb = swz16(b);       a = fmaxf(a, ta); b = fmaxf(b, tb);
}
__device__ __forceinline__ void redsum32x2(float& a, float& b) {
    float ta, tb;
    ta = dppf<0xB1>(a);  tb = dppf<0xB1>(b);  a += ta; b += tb;
    ta = dppf<0x4E>(a);  tb = dppf<0x4E>(b);  a += ta; b += tb;
    ta = dppf<0x141>(a); tb = dppf<0x141>(b); a += ta; b += tb;
    ta = dppf<0x140>(a); tb = dppf<0x140>(b); a += ta; b += tb;
    ta = swz16(a);       tb = swz16(b);       a += ta; b += tb;
}

__global__ __launch_bounds__(512, 4)
void caps_em_kernel(const float* __restrict__ x,
                    const float* __restrict__ Wg,
                    const float* __restrict__ bu,
                    const float* __restrict__ ba,
                    float* __restrict__ out)
{
    // LDS: 18432 + 1152 + 33792 + 2176 + 2176 + 256 = 57984 B -> 2 blocks/CU
    __shared__ float p4[NKK * 16];       // pose fragments [k*16+p]
    __shared__ float cIn[NKK];           // a/(a+eps)
    __shared__ float scr[8 * 32 * 33];   // [g][o][ Sv(16) | Sv2(16) | S0 ]
    __shared__ float meanS[32 * 17];     // mean[o*17+p]  (stride 17: conflict-free)
    __shared__ float i2vS[32 * 17];      // 1/(2*std^2)
    __shared__ float actS[32];
    __shared__ float baseS[32];          // log(act) - sum_p log std - 8*ln2pi

    const int n = blockIdx.x;
    const int t = threadIdx.x;

    // ---- gather poses: flat view of tiled (B,kh,kw,oh,ow,512) ----
    for (int idx = t; idx < NKK * 16; idx += 512) {
        unsigned g = (unsigned)n * 4608u + (unsigned)idx;
        unsigned c = g & 511u, rest = g >> 9;
        unsigned ow = rest % 7u; rest /= 7u;
        unsigned oh = rest % 7u; rest /= 7u;
        unsigned kw = rest % 3u; rest /= 3u;
        unsigned kh = rest % 3u;
        unsigned b  = rest / 3u;
        p4[idx] = x[((b*16u + 2u*oh + kh)*16u + 2u*ow + kw)*544u + c];
    }
    // ---- gather acts -> c_k ----
    for (int idx = t; idx < NKK; idx += 512) {
        unsigned g = (unsigned)n * 288u + (unsigned)idx;
        unsigned c = g & 31u, rest = g >> 5;
        unsigned ow = rest % 7u; rest /= 7u;
        unsigned oh = rest % 7u; rest /= 7u;
        unsigned kw = rest % 3u; rest /= 3u;
        unsigned kh = rest % 3u;
        unsigned b  = rest / 3u;
        const float a = x[((b*16u + 2u*oh + kh)*16u + 2u*ow + kw)*544u + 512u + c];
        cIn[idx] = a / (a + EPSF);
    }
    __syncthreads();

    const int o  = t & 31;    // out-cap (== lane&31)
    const int kc = t >> 5;    // k-chunk 0..15 (18 k each)
    const int oo = t >> 4;    // reducer row 0..31
    const int pp = t & 15;    // reducer col 0..15

    float lam = 1.0e-3f;

    for (int it = 0; it < 3; ++it) {
        lam += 1.0e-4f;

        float S0 = 0.f, Sv[16], Sv2[16];
        #pragma unroll
        for (int p = 0; p < 16; ++p) { Sv[p] = 0.f; Sv2[p] = 0.f; }

        if (it == 0) {
            // ---- M0: uniform r -> u_k = c_k/32 (same for all o) ----
            #pragma unroll 2
            for (int kk = 0; kk < 18; ++kk) {
                const int k = kc*18 + kk;
                const float w = cIn[k] * 0.03125f;
                float P[16], Wl[16];
                #pragma unroll
                for (int p = 0; p < 16; p += 4) {
                    const float4 v4 = *(const float4*)&p4[k*16 + p];
                    P[p] = v4.x; P[p+1] = v4.y; P[p+2] = v4.z; P[p+3] = v4.w;
                    const float4 w4 = *(const float4*)&Wg[(k*32 + o)*16 + p];
                    Wl[p] = w4.x; Wl[p+1] = w4.y; Wl[p+2] = w4.z; Wl[p+3] = w4.w;
                }
                S0 += w;
                #pragma unroll
                for (int i = 0; i < 4; ++i) {
                    #pragma unroll
                    for (int m = 0; m < 4; ++m) {
                        float v = P[i*4] * Wl[m];
                        v = fmaf(P[i*4+1], Wl[4+m],  v);
                        v = fmaf(P[i*4+2], Wl[8+m],  v);
                        v = fmaf(P[i*4+3], Wl[12+m], v);
                        const float wv = w * v;
                        Sv [i*4+m] += wv;
                        Sv2[i*4+m]  = fmaf(wv, v, Sv2[i*4+m]);
                    }
                }
            }
        } else {
            // ---- fused E(prev stats) + M accumulate, dual-k for ILP ----
            float M[16], I[16];
            #pragma unroll
            for (int p = 0; p < 16; ++p) { M[p] = meanS[o*17 + p]; I[p] = i2vS[o*17 + p]; }
            const float base = baseS[o];
            #pragma unroll 1
            for (int kk = 0; kk < 18; kk += 2) {
                const int k0 = kc*18 + kk;
                const int k1 = k0 + 1;
                float v0[16], v1[16];
                float lnp0, lnp1;
                // ---- chain 0: votes + sacc for k0 (P/Wl die after) ----
                {
                    float P[16], Wl[16];
                    #pragma unroll
                    for (int p = 0; p < 16; p += 4) {
                        const float4 v4 = *(const float4*)&p4[k0*16 + p];
                        P[p] = v4.x; P[p+1] = v4.y; P[p+2] = v4.z; P[p+3] = v4.w;
                        const float4 w4 = *(const float4*)&Wg[(k0*32 + o)*16 + p];
                        Wl[p] = w4.x; Wl[p+1] = w4.y; Wl[p+2] = w4.z; Wl[p+3] = w4.w;
                    }
                    float sa0 = 0.f, sa1 = 0.f, sa2 = 0.f, sa3 = 0.f;
                    #pragma unroll
                    for (int i = 0; i < 4; ++i) {
                        float sa = 0.f;
                        #pragma unroll
                        for (int m = 0; m < 4; ++m) {
                            float vv = P[i*4] * Wl[m];
                            vv = fmaf(P[i*4+1], Wl[4+m],  vv);
                            vv = fmaf(P[i*4+2], Wl[8+m],  vv);
                            vv = fmaf(P[i*4+3], Wl[12+m], vv);
                            v0[i*4+m] = vv;
                            const float d = vv - M[i*4+m];
                            sa = fmaf(d*d, I[i*4+m], sa);
                        }
                        if (i == 0) sa0 = sa; else if (i == 1) sa1 = sa;
                        else if (i == 2) sa2 = sa; else sa3 = sa;
                    }
                    lnp0 = base - ((sa0 + sa1) + (sa2 + sa3));
                }
                // ---- chain 1: votes + sacc for k1 ----
                {
                    float P[16], Wl[16];
                    #pragma unroll
                    for (int p = 0; p < 16; p += 4) {
                        const float4 v4 = *(const float4*)&p4[k1*16 + p];
                        P[p] = v4.x; P[p+1] = v4.y; P[p+2] = v4.z; P[p+3] = v4.w;
                        const float4 w4 = *(const float4*)&Wg[(k1*32 + o)*16 + p];
                        Wl[p] = w4.x; Wl[p+1] = w4.y; Wl[p+2] = w4.z; Wl[p+3] = w4.w;
                    }
                    float sa0 = 0.f, sa1 = 0.f, sa2 = 0.f, sa3 = 0.f;
                    #pragma unroll
                    for (int i = 0; i < 4; ++i) {
                        float sa = 0.f;
                        #pragma unroll
                        for (int m = 0; m < 4; ++m) {
                            float vv = P[i*4] * Wl[m];
                            vv = fmaf(P[i*4+1], Wl[4+m],  vv);
                            vv = fmaf(P[i*4+2], Wl[8+m],  vv);
                            vv = fmaf(P[i*4+3], Wl[12+m], vv);
                            v1[i*4+m] = vv;
                            const float d = vv - M[i*4+m];
                            sa = fmaf(d*d, I[i*4+m], sa);
                        }
                        if (i == 0) sa0 = sa; else if (i == 1) sa1 = sa;
                        else if (i == 2) sa2 = sa; else sa3 = sa;
                    }
                    lnp1 = base - ((sa0 + sa1) + (sa2 + sa3));
                }
                // ---- dual softmax over the 32 o's (interleaved chains) ----
                float mx0 = lnp0, mx1 = lnp1;
                redmax32x2(mx0, mx1);
                float e0 = __expf(lnp0 - mx0);
                float e1 = __expf(lnp1 - mx1);
                float ss0 = e0, ss1 = e1;
                redsum32x2(ss0, ss1);
                const float u0 = e0 * fastrcp(ss0) * cIn[k0];
                const float u1 = e1 * fastrcp(ss1) * cIn[k1];
                S0 += u0 + u1;
                #pragma unroll
                for (int p = 0; p < 16; ++p) {
                    const float uv0 = u0 * v0[p];
                    const float uv1 = u1 * v1[p];
                    Sv [p] += uv0 + uv1;
                    Sv2[p]  = fmaf(uv0, v0[p], fmaf(uv1, v1[p], Sv2[p]));
                }
            }
        }

        // ---- combine kc pairs (partner lane^32, same wave) -> 8 groups ----
        S0 += __shfl_xor(S0, 32, 64);
        #pragma unroll
        for (int p = 0; p < 16; ++p) {
            Sv [p] += __shfl_xor(Sv [p], 32, 64);
            Sv2[p] += __shfl_xor(Sv2[p], 32, 64);
        }
        if ((kc & 1) == 0) {
            float* row = &scr[((kc >> 1)*32 + o)*33];
            #pragma unroll
            for (int p = 0; p < 16; ++p) { row[p] = Sv[p]; row[16 + p] = Sv2[p]; }
            row[32] = S0;
        }
        __syncthreads();

        // ---- reduce 8 groups + stats; thread t handles (oo, pp) ----
        {
            float sm = 0.f, s2 = 0.f, rs = 0.f;
            #pragma unroll
            for (int q = 0; q < 8; ++q) {
                const int b0 = (q*32 + oo)*33;
                sm += scr[b0 + pp];
                s2 += scr[b0 + 16 + pp];
                rs += scr[b0 + 32];
            }
            const float inv = 1.0f / (rs + EPSF);
            const float S1  = rs * inv;
            const float m   = sm * inv;
            float var = s2 * inv - m*m*(2.0f - S1);
            var = fmaxf(var, 0.0f) + EPSF;          // std^2 (+eps inside sqrt)
            meanS[oo*17 + pp] = m;
            i2vS [oo*17 + pp] = 0.5f / var;
            scr[oo*33 + pp] = 0.5f * __logf(var);   // log std; q=0 slot owned by this thread
        }
        __syncthreads();
        if (t < 32) {
            float lsum = 0.f;
            #pragma unroll
            for (int p = 0; p < 16; ++p) lsum += scr[t*33 + p];
            float rs = 0.f;
            #pragma unroll
            for (int q = 0; q < 8; ++q) rs += scr[(q*32 + t)*33 + 32];
            const float cost = (16.0f * bu[t] + lsum) * rs;
            const float ao   = 1.0f / (1.0f + __expf(-lam * (ba[t] - cost)));
            actS[t]  = ao;
            baseS[t] = -lsum - 8.0f*LN2PI + __logf(ao);
        }
        __syncthreads();
    }

    // ---- output: [mean(512) | act(32)] per n ----
    for (int idx = t; idx < 544; idx += 512) {
        const float v = (idx < 512) ? meanS[(idx >> 4)*17 + (idx & 15)]
                                    : actS[idx - 512];
        out[n*544 + idx] = v;
    }
}

} // namespace

extern "C" void kernel_launch(void* const* d_in, const int* in_sizes, int n_in,
                              void* d_out, int out_size, void* d_ws, size_t ws_size,
                              hipStream_t stream) {
    (void)in_sizes; (void)n_in; (void)out_size; (void)d_ws; (void)ws_size;
    const float* x  = (const float*)d_in[0];
    const float* W  = (const float*)d_in[1];
    const float* bu = (const float*)d_in[2];
    const float* ba = (const float*)d_in[3];
    float* out = (float*)d_out;
    caps_em_kernel<<<dim3(392), dim3(512), 0, stream>>>(x, W, bu, ba, out);
}

// Round 4
// 126.044 us; speedup vs baseline: 2.0490x; 2.0490x over previous
//
#include <hip/hip_runtime.h>

// ConvCaps EM-routing, MI355X. 392 independent problems, one 512-thread block each.
// Thread = (o = t&31 out-cap, kc = t>>5 of 16 k-chunks, 18 k each).
// __launch_bounds__(512,4). Register file is FULLY COMMITTED at this config:
// dual-k ILP (round 3) and 1024-thread (round 1) both spilled to scratch
// (FETCH 272 MB / 675 MB). Grid is only 392 blocks -> occupancy ceiling 38%.
// So: reduce VALU instruction count at CONSTANT register pressure via packed
// fp32 (v_pk_fma_f32 etc., full-rate on CDNA): votes/sacc/accumulation operate
// on f32x2 pairs -> ~45% fewer VALU ops in the hot k-body.
// Fused E+M: votes recomputed only 3x (M0, E0+M1, E1+M2) using unnormalized
// moments  mean = S(uv)/(rs+eps), var = S(uv^2)/(rs+eps) - m^2(2-S1),
// u_k = softmax_o(ln_ap)*c_k, c_k = a/(a+eps). r-matrix never materialized.
// Softmax 32-lane reduces: DPP basis {xor1,xor2,xor7,xor15} + ds_swizzle xor16.

namespace {

constexpr int NKK = 288;
constexpr float EPSF = 1e-8f;
constexpr float LN2PI = 1.8378770664093453f;

typedef float f32x2 __attribute__((ext_vector_type(2)));

__device__ __forceinline__ float fastrcp(float x) { return __builtin_amdgcn_rcpf(x); }
__device__ __forceinline__ f32x2 splat2(float x) { f32x2 r; r.x = x; r.y = x; return r; }
__device__ __forceinline__ f32x2 fma2(f32x2 a, f32x2 b, f32x2 c) {
    return __builtin_elementwise_fma(a, b, c);
}

// DPP lane permute (VALU pipe). CTRL: 0xB1=quad_perm xor1, 0x4E=quad_perm xor2,
// 0x141=row_half_mirror (xor7), 0x140=row_mirror (xor15).
template <int CTRL>
__device__ __forceinline__ float dppf(float x) {
    return __int_as_float(__builtin_amdgcn_update_dpp(
        __float_as_int(x), __float_as_int(x), CTRL, 0xF, 0xF, false));
}
// ds_swizzle xor16 within each 32-lane group (bitmode: xor=16, and=0x1F).
__device__ __forceinline__ float swz16(float x) {
    return __int_as_float(__builtin_amdgcn_ds_swizzle(__float_as_int(x), 0x401F));
}

// Reduce over the 32-lane group (lanes 0-31 / 32-63 independently).
// XOR-mask basis {1,2,7,15,16} spans bits 0..4 -> valid butterfly.
__device__ __forceinline__ float redmax32(float v) {
    v = fmaxf(v, dppf<0xB1>(v));
    v = fmaxf(v, dppf<0x4E>(v));
    v = fmaxf(v, dppf<0x141>(v));
    v = fmaxf(v, dppf<0x140>(v));
    v = fmaxf(v, swz16(v));
    return v;
}
__device__ __forceinline__ float redsum32(float v) {
    v += dppf<0xB1>(v);
    v += dppf<0x4E>(v);
    v += dppf<0x141>(v);
    v += dppf<0x140>(v);
    v += swz16(v);
    return v;
}

__global__ __launch_bounds__(512, 4)
void caps_em_kernel(const float* __restrict__ x,
                    const float* __restrict__ Wg,
                    const float* __restrict__ bu,
                    const float* __restrict__ ba,
                    float* __restrict__ out)
{
    // LDS: 18432 + 1152 + 33792 + 2176 + 2176 + 256 = 57984 B -> 2 blocks/CU
    __shared__ float p4[NKK * 16];       // pose fragments [k*16+p]
    __shared__ float cIn[NKK];           // a/(a+eps)
    __shared__ float scr[8 * 32 * 33];   // [g][o][ Sv(16) | Sv2(16) | S0 ]
    __shared__ float meanS[32 * 17];     // mean[o*17+p]  (stride 17: conflict-free)
    __shared__ float i2vS[32 * 17];      // 1/(2*std^2)
    __shared__ float actS[32];
    __shared__ float baseS[32];          // log(act) - sum_p log std - 8*ln2pi

    const int n = blockIdx.x;
    const int t = threadIdx.x;

    // ---- gather poses: flat view of tiled (B,kh,kw,oh,ow,512) ----
    for (int idx = t; idx < NKK * 16; idx += 512) {
        unsigned g = (unsigned)n * 4608u + (unsigned)idx;
        unsigned c = g & 511u, rest = g >> 9;
        unsigned ow = rest % 7u; rest /= 7u;
        unsigned oh = rest % 7u; rest /= 7u;
        unsigned kw = rest % 3u; rest /= 3u;
        unsigned kh = rest % 3u;
        unsigned b  = rest / 3u;
        p4[idx] = x[((b*16u + 2u*oh + kh)*16u + 2u*ow + kw)*544u + c];
    }
    // ---- gather acts -> c_k ----
    for (int idx = t; idx < NKK; idx += 512) {
        unsigned g = (unsigned)n * 288u + (unsigned)idx;
        unsigned c = g & 31u, rest = g >> 5;
        unsigned ow = rest % 7u; rest /= 7u;
        unsigned oh = rest % 7u; rest /= 7u;
        unsigned kw = rest % 3u; rest /= 3u;
        unsigned kh = rest % 3u;
        unsigned b  = rest / 3u;
        const float a = x[((b*16u + 2u*oh + kh)*16u + 2u*ow + kw)*544u + 512u + c];
        cIn[idx] = a / (a + EPSF);
    }
    __syncthreads();

    const int o  = t & 31;    // out-cap (== lane&31)
    const int kc = t >> 5;    // k-chunk 0..15 (18 k each)
    const int oo = t >> 4;    // reducer row 0..31
    const int pp = t & 15;    // reducer col 0..15

    float lam = 1.0e-3f;

    for (int it = 0; it < 3; ++it) {
        lam += 1.0e-4f;

        float S0 = 0.f;
        f32x2 Svp[8], Sv2p[8];
        #pragma unroll
        for (int q = 0; q < 8; ++q) { Svp[q] = splat2(0.f); Sv2p[q] = splat2(0.f); }

        if (it == 0) {
            // ---- M0: uniform r -> u_k = c_k/32 (same for all o) ----
            #pragma unroll 2
            for (int kk = 0; kk < 18; ++kk) {
                const int k = kc*18 + kk;
                const float w = cIn[k] * 0.03125f;
                const f32x2 w2 = splat2(w);
                float P[16]; f32x2 Wl2[8];
                #pragma unroll
                for (int j = 0; j < 4; ++j) {
                    const float4 v4 = *(const float4*)&p4[k*16 + 4*j];
                    P[4*j] = v4.x; P[4*j+1] = v4.y; P[4*j+2] = v4.z; P[4*j+3] = v4.w;
                    const float4 w4 = *(const float4*)&Wg[(k*32 + o)*16 + 4*j];
                    f32x2 lo; lo.x = w4.x; lo.y = w4.y;
                    f32x2 hi; hi.x = w4.z; hi.y = w4.w;
                    Wl2[2*j] = lo; Wl2[2*j+1] = hi;
                }
                S0 += w;
                #pragma unroll
                for (int i = 0; i < 4; ++i) {
                    #pragma unroll
                    for (int h = 0; h < 2; ++h) {
                        const int q = i*2 + h;
                        f32x2 acc = splat2(P[i*4]) * Wl2[h];
                        acc = fma2(splat2(P[i*4+1]), Wl2[2+h], acc);
                        acc = fma2(splat2(P[i*4+2]), Wl2[4+h], acc);
                        acc = fma2(splat2(P[i*4+3]), Wl2[6+h], acc);
                        const f32x2 wv = w2 * acc;
                        Svp[q] += wv;
                        Sv2p[q] = fma2(wv, acc, Sv2p[q]);
                    }
                }
            }
        } else {
            // ---- fused E(prev stats) + M accumulate, packed fp32 ----
            f32x2 M2[8], I2[8];
            #pragma unroll
            for (int q = 0; q < 8; ++q) {
                f32x2 m; m.x = meanS[o*17 + 2*q]; m.y = meanS[o*17 + 2*q + 1];
                f32x2 iv; iv.x = i2vS[o*17 + 2*q]; iv.y = i2vS[o*17 + 2*q + 1];
                M2[q] = m; I2[q] = iv;
            }
            const float base = baseS[o];
            for (int kk = 0; kk < 18; ++kk) {
                const int k = kc*18 + kk;
                float P[16]; f32x2 Wl2[8];
                #pragma unroll
                for (int j = 0; j < 4; ++j) {
                    const float4 v4 = *(const float4*)&p4[k*16 + 4*j];
                    P[4*j] = v4.x; P[4*j+1] = v4.y; P[4*j+2] = v4.z; P[4*j+3] = v4.w;
                    const float4 w4 = *(const float4*)&Wg[(k*32 + o)*16 + 4*j];
                    f32x2 lo; lo.x = w4.x; lo.y = w4.y;
                    f32x2 hi; hi.x = w4.z; hi.y = w4.w;
                    Wl2[2*j] = lo; Wl2[2*j+1] = hi;
                }
                f32x2 v2[8];
                f32x2 sa[4];
                #pragma unroll
                for (int i = 0; i < 4; ++i) {
                    sa[i] = splat2(0.f);
                    #pragma unroll
                    for (int h = 0; h < 2; ++h) {
                        const int q = i*2 + h;
                        f32x2 acc = splat2(P[i*4]) * Wl2[h];
                        acc = fma2(splat2(P[i*4+1]), Wl2[2+h], acc);
                        acc = fma2(splat2(P[i*4+2]), Wl2[4+h], acc);
                        acc = fma2(splat2(P[i*4+3]), Wl2[6+h], acc);
                        v2[q] = acc;
                        const f32x2 d = acc - M2[q];
                        sa[i] = fma2(d * d, I2[q], sa[i]);
                    }
                }
                const f32x2 sv = (sa[0] + sa[1]) + (sa[2] + sa[3]);
                const float lnp = base - (sv.x + sv.y);
                // softmax over the 32 o's in this half-wave (DPP + 1 swizzle each)
                const float mx = redmax32(lnp);
                const float e  = __expf(lnp - mx);
                const float ss = redsum32(e);
                const float u = e * fastrcp(ss) * cIn[k];
                S0 += u;
                const f32x2 u2 = splat2(u);
                #pragma unroll
                for (int q = 0; q < 8; ++q) {
                    const f32x2 uv = u2 * v2[q];
                    Svp[q] += uv;
                    Sv2p[q] = fma2(uv, v2[q], Sv2p[q]);
                }
            }
        }

        // ---- combine kc pairs (partner lane^32, same wave) -> 8 groups ----
        S0 += __shfl_xor(S0, 32, 64);
        #pragma unroll
        for (int q = 0; q < 8; ++q) {
            f32x2 ta, tb;
            ta.x = __shfl_xor(Svp[q].x, 32, 64);
            ta.y = __shfl_xor(Svp[q].y, 32, 64);
            tb.x = __shfl_xor(Sv2p[q].x, 32, 64);
            tb.y = __shfl_xor(Sv2p[q].y, 32, 64);
            Svp[q] += ta;
            Sv2p[q] += tb;
        }
        if ((kc & 1) == 0) {
            float* row = &scr[((kc >> 1)*32 + o)*33];
            #pragma unroll
            for (int q = 0; q < 8; ++q) {
                row[2*q]      = Svp[q].x;  row[2*q + 1]      = Svp[q].y;
                row[16 + 2*q] = Sv2p[q].x; row[16 + 2*q + 1] = Sv2p[q].y;
            }
            row[32] = S0;
        }
        __syncthreads();

        // ---- reduce 8 groups + stats; thread t handles (oo, pp) ----
        {
            float sm = 0.f, s2 = 0.f, rs = 0.f;
            #pragma unroll
            for (int q = 0; q < 8; ++q) {
                const int b0 = (q*32 + oo)*33;
                sm += scr[b0 + pp];
                s2 += scr[b0 + 16 + pp];
                rs += scr[b0 + 32];
            }
            const float inv = 1.0f / (rs + EPSF);
            const float S1  = rs * inv;
            const float m   = sm * inv;
            float var = s2 * inv - m*m*(2.0f - S1);
            var = fmaxf(var, 0.0f) + EPSF;          // std^2 (+eps inside sqrt)
            meanS[oo*17 + pp] = m;
            i2vS [oo*17 + pp] = 0.5f / var;
            scr[oo*33 + pp] = 0.5f * __logf(var);   // log std; q=0 slot owned by this thread
        }
        __syncthreads();
        if (t < 32) {
            float lsum = 0.f;
            #pragma unroll
            for (int p = 0; p < 16; ++p) lsum += scr[t*33 + p];
            float rs = 0.f;
            #pragma unroll
            for (int q = 0; q < 8; ++q) rs += scr[(q*32 + t)*33 + 32];
            const float cost = (16.0f * bu[t] + lsum) * rs;
            const float ao   = 1.0f / (1.0f + __expf(-lam * (ba[t] - cost)));
            actS[t]  = ao;
            baseS[t] = -lsum - 8.0f*LN2PI + __logf(ao);
        }
        __syncthreads();
    }

    // ---- output: [mean(512) | act(32)] per n ----
    for (int idx = t; idx < 544; idx += 512) {
        const float v = (idx < 512) ? meanS[(idx >> 4)*17 + (idx & 15)]
                                    : actS[idx - 512];
        out[n*544 + idx] = v;
    }
}

} // namespace

extern "C" void kernel_launch(void* const* d_in, const int* in_sizes, int n_in,
                              void* d_out, int out_size, void* d_ws, size_t ws_size,
                              hipStream_t stream) {
    (void)in_sizes; (void)n_in; (void)out_size; (void)d_ws; (void)ws_size;
    const float* x  = (const float*)d_in[0];
    const float* W  = (const float*)d_in[1];
    const float* bu = (const float*)d_in[2];
    const float* ba = (const float*)d_in[3];
    float* out = (float*)d_out;
    caps_em_kernel<<<dim3(392), dim3(512), 0, stream>>>(x, W, bu, ba, out);
}